// Round 3
// baseline (1910.336 us; speedup 1.0000x reference)
//
#include <hip/hip_runtime.h>
#include <cstddef>

#define Bz 8
#define Nn 16384
#define MD 256
#define Ff 32
#define Hh 4
#define Gg 32
#define G3v 32768
#define CKV 140
#define NG 32          // B*H groups
#define NBIN 31        // x0 bins per group (x0 in [0,30])

// ---------------- Pass 1: kv = W·X (per batch), fused BN statistics ----------------
__global__ __launch_bounds__(256) void gemm_stats_kernel(
    const float* __restrict__ X, const float* __restrict__ W,
    float* __restrict__ vals, float* __restrict__ keys,
    float* __restrict__ gsum, float* __restrict__ gsq)
{
    __shared__ float Xs[64][64];
    __shared__ float Ws[64][161];
    __shared__ float red[280];

    const int bid = blockIdx.x;
    const int b   = bid >> 8;
    const int n0  = (bid & 255) << 6;
    const int t   = threadIdx.x;
    const int tx  = t & 31;
    const int ty  = t >> 5;

    float acc[5][8];
    #pragma unroll
    for (int i = 0; i < 5; ++i)
        #pragma unroll
        for (int j = 0; j < 8; ++j) acc[i][j] = 0.f;

    for (int k0 = 0; k0 < MD; k0 += 64) {
        {
            const int r  = t >> 4;
            const int c4 = (t & 15) << 2;
            #pragma unroll
            for (int i = 0; i < 4; ++i) {
                const int k = r + i * 16;
                const float4 v = *reinterpret_cast<const float4*>(
                    X + (size_t)(b * MD + k0 + k) * Nn + n0 + c4);
                *reinterpret_cast<float4*>(&Xs[k][c4]) = v;
            }
        }
        for (int idx = t; idx < 64 * 160; idx += 256) {
            const int c = idx >> 6;
            const int k = idx & 63;
            Ws[k][c] = (c < CKV) ? W[c * MD + k0 + k] : 0.f;
        }
        __syncthreads();

        for (int k = 0; k < 64; ++k) {
            float xv[8];
            *reinterpret_cast<float4*>(&xv[0]) = *reinterpret_cast<const float4*>(&Xs[k][ty * 8]);
            *reinterpret_cast<float4*>(&xv[4]) = *reinterpret_cast<const float4*>(&Xs[k][ty * 8 + 4]);
            const float w0 = Ws[k][tx];
            const float w1 = Ws[k][tx + 32];
            const float w2 = Ws[k][tx + 64];
            const float w3 = Ws[k][tx + 96];
            const float w4 = Ws[k][tx + 128];
            #pragma unroll
            for (int j = 0; j < 8; ++j) {
                acc[0][j] = fmaf(w0, xv[j], acc[0][j]);
                acc[1][j] = fmaf(w1, xv[j], acc[1][j]);
                acc[2][j] = fmaf(w2, xv[j], acc[2][j]);
                acc[3][j] = fmaf(w3, xv[j], acc[3][j]);
                acc[4][j] = fmaf(w4, xv[j], acc[4][j]);
            }
        }
        __syncthreads();
    }

    const int nb = n0 + ty * 8;
    #pragma unroll
    for (int cg = 0; cg < 5; ++cg) {
        const int c = tx + 32 * cg;
        if (c >= CKV) continue;
        if (c < 12) {
            const int hh = c / 3, kk = c - (c / 3) * 3;
            float* dst = keys + (size_t)((b * Hh + hh) * 3 + kk) * Nn + nb;
            #pragma unroll
            for (int j = 0; j < 8; ++j) dst[j] = acc[cg][j];
        } else {
            const int cv = c - 12;
            const int hh = cv >> 5, f = cv & 31;
            float* dst = vals + ((size_t)(b * Hh + hh) * Nn + nb) * Ff + f;
            #pragma unroll
            for (int j = 0; j < 8; ++j) dst[(size_t)j * Ff] = acc[cg][j];
        }
    }

    red[t] = 0.f;
    if (t < 24) red[256 + t] = 0.f;
    __syncthreads();
    #pragma unroll
    for (int cg = 0; cg < 5; ++cg) {
        const int c = tx + 32 * cg;
        if (c >= CKV) continue;
        float s = 0.f, q = 0.f;
        #pragma unroll
        for (int j = 0; j < 8; ++j) { s += acc[cg][j]; q = fmaf(acc[cg][j], acc[cg][j], q); }
        atomicAdd(&red[c], s);
        atomicAdd(&red[140 + c], q);
    }
    __syncthreads();
    if (t < CKV) {
        atomicAdd(&gsum[t], red[t]);
        atomicAdd(&gsq[t],  red[140 + t]);
    }
}

// ---------------- Pass 2: finalize BN affine params ----------------
__global__ void finalize_kernel(const float* __restrict__ gsum, const float* __restrict__ gsq,
                                const float* __restrict__ kg, const float* __restrict__ kb,
                                const float* __restrict__ vg, const float* __restrict__ vb,
                                float* __restrict__ scale, float* __restrict__ shift)
{
    const int c = threadIdx.x;
    if (c < CKV) {
        const float inv = 1.f / (float)(Bz * Nn);
        const float m = gsum[c] * inv;
        const float v = fmaf(-m, m, gsq[c] * inv);
        float ga, be;
        if (c < 12) { ga = kg[c]; be = kb[c]; }
        else        { ga = vg[c - 12]; be = vb[c - 12]; }
        const float sc = ga * rsqrtf(v + 1e-5f);
        scale[c] = sc;
        shift[c] = fmaf(-m, sc, be);
    }
}

// ---------------- Pass 3a: per-point transform -> record + bin histogram ----------------
// record: {meta = n | y0<<14 | z0<<19 | x0<<24, lx, ly, lz}
__global__ __launch_bounds__(256) void points_kernel(
    const float* __restrict__ keys, const float* __restrict__ orig,
    const float* __restrict__ Rm, const float* __restrict__ tv,
    const float* __restrict__ scale, const float* __restrict__ shift,
    float4* __restrict__ rec, int* __restrict__ cnt)
{
    const int bid = blockIdx.x;
    const int g   = bid >> 6;
    const int b   = g >> 2;
    const int h   = g & 3;
    const int t   = threadIdx.x;
    const int n   = ((bid & 63) << 8) + t;

    __shared__ float sR[9], st3[3], ksc[3], ksh[3];
    if (t < 9)       sR[t] = Rm[h * 9 + t];
    else if (t < 12) st3[t - 9] = tv[h * 3 + (t - 9)];
    else if (t < 15) { ksc[t - 12] = scale[h * 3 + (t - 12)];
                       ksh[t - 12] = shift[h * 3 + (t - 12)]; }
    __syncthreads();

    const float k0 = fmaf(keys[(size_t)(g * 3 + 0) * Nn + n], ksc[0], ksh[0]);
    const float k1 = fmaf(keys[(size_t)(g * 3 + 1) * Nn + n], ksc[1], ksh[1]);
    const float k2 = fmaf(keys[(size_t)(g * 3 + 2) * Nn + n], ksc[2], ksh[2]);
    const float p0 = orig[(size_t)(b * 3 + 0) * Nn + n] + k0;
    const float p1 = orig[(size_t)(b * 3 + 1) * Nn + n] + k1;
    const float p2 = orig[(size_t)(b * 3 + 2) * Nn + n] + k2;

    int   idx[3];
    float loc[3];
    #pragma unroll
    for (int d = 0; d < 3; ++d) {
        const float tk = fmaf(sR[d*3+0], p0, fmaf(sR[d*3+1], p1, fmaf(sR[d*3+2], p2, st3[d])));
        const float la = tanhf(tk);
        const float po = (la + 1.f) * 15.5f;
        float fi = floorf(po);
        fi = fminf(fmaxf(fi, 0.f), 30.f);
        idx[d] = (int)fi;
        loc[d] = po - fi;
    }

    const unsigned meta = (unsigned)n | ((unsigned)idx[1] << 14) |
                          ((unsigned)idx[2] << 19) | ((unsigned)idx[0] << 24);
    float4 r;
    r.x = __uint_as_float(meta);
    r.y = loc[0]; r.z = loc[1]; r.w = loc[2];
    rec[(size_t)g * Nn + n] = r;
    atomicAdd(&cnt[g * NBIN + idx[0]], 1);
}

// ---------------- Pass 3b: exclusive scan over 992 bins ----------------
__global__ void scan_kernel(const int* __restrict__ cnt,
                            int* __restrict__ base, int* __restrict__ cursor)
{
    __shared__ int s[1024];
    const int t = threadIdx.x;   // 1024 threads
    const int own = (t < NG * NBIN) ? cnt[t] : 0;
    s[t] = own;
    __syncthreads();
    for (int off = 1; off < 1024; off <<= 1) {
        const int x = (t >= off) ? s[t - off] : 0;
        __syncthreads();
        s[t] += x;
        __syncthreads();
    }
    if (t < NG * NBIN) {
        const int e = s[t] - own;   // exclusive
        base[t] = e;
        cursor[t] = e;
    }
}

// ---------------- Pass 3c: counting-sort records into bins ----------------
__global__ __launch_bounds__(256) void fill_kernel(
    const float4* __restrict__ rec, int* __restrict__ cursor,
    float4* __restrict__ binned)
{
    const int bid = blockIdx.x;
    const int g   = bid >> 6;
    const int t   = threadIdx.x;
    const int n   = ((bid & 63) << 8) + t;
    const float4 r = rec[(size_t)g * Nn + n];
    const unsigned meta = __float_as_uint(r.x);
    const int x0 = (meta >> 24) & 31;
    const int pos = atomicAdd(&cursor[g * NBIN + x0], 1);
    binned[pos] = r;
}

// ---------------- Pass 3d: per-plane LDS accumulate + direct write-out ----------------
// Grid: 1024 blocks = 32 g x 32 planes; 512 threads = 16 groups x 32 lanes.
// LDS 128 KiB = one plane [yz][f] with XOR swizzle (f^yz) -> conflict-free both phases.
__global__ __launch_bounds__(512) void plane_kernel(
    const float* __restrict__ vals, const float4* __restrict__ binned,
    const int* __restrict__ base, const int* __restrict__ cnt,
    const float* __restrict__ scale, const float* __restrict__ shift,
    float* __restrict__ out)
{
    __shared__ float acc[32768];
    __shared__ float sscale[32], sshift[32];

    const int bid   = blockIdx.x;
    const int g     = bid >> 5;
    const int plane = bid & 31;
    const int h     = g & 3;
    const int t     = threadIdx.x;

    for (int i = t; i < 32768; i += 512) acc[i] = 0.f;
    if (t < 32) { sscale[t] = scale[12 + h * 32 + t]; sshift[t] = shift[12 + h * 32 + t]; }
    __syncthreads();

    const int f   = t & 31;
    const int grp = t >> 5;      // 16 groups
    const float scf = sscale[f], shf = sshift[f];
    const float* vg = vals + ((size_t)g << 19);   // g * Nn * Ff

    #pragma unroll
    for (int part = 0; part < 2; ++part) {
        const int x0 = plane - part;
        if (x0 < 0 || x0 > 30) continue;
        const int bin = g * NBIN + x0;
        const int s = base[bin];
        const int e = s + cnt[bin];

        int r = s + grp;
        for (; r + 16 < e; r += 32) {
            const float4 ra = binned[r];
            const float4 rb = binned[r + 16];
            const unsigned ma = __float_as_uint(ra.x);
            const unsigned mb = __float_as_uint(rb.x);
            const float va = vg[(((size_t)(ma & 16383)) << 5) + f];
            const float vb = vg[(((size_t)(mb & 16383)) << 5) + f];

            {
                const int y0 = (ma >> 14) & 31, z0 = (ma >> 19) & 31;
                const float v  = fmaf(va, scf, shf);
                const float wx = part ? ra.y : 1.f - ra.y;
                const float wy[2] = { 1.f - ra.z, ra.z };
                const float wz[2] = { 1.f - ra.w, ra.w };
                #pragma unroll
                for (int cy = 0; cy < 2; ++cy)
                    #pragma unroll
                    for (int cz = 0; cz < 2; ++cz) {
                        const int yz = ((y0 + cy) << 5) + z0 + cz;
                        atomicAdd(&acc[(yz << 5) | ((f ^ yz) & 31)], wx * wy[cy] * wz[cz] * v);
                    }
            }
            {
                const int y0 = (mb >> 14) & 31, z0 = (mb >> 19) & 31;
                const float v  = fmaf(vb, scf, shf);
                const float wx = part ? rb.y : 1.f - rb.y;
                const float wy[2] = { 1.f - rb.z, rb.z };
                const float wz[2] = { 1.f - rb.w, rb.w };
                #pragma unroll
                for (int cy = 0; cy < 2; ++cy)
                    #pragma unroll
                    for (int cz = 0; cz < 2; ++cz) {
                        const int yz = ((y0 + cy) << 5) + z0 + cz;
                        atomicAdd(&acc[(yz << 5) | ((f ^ yz) & 31)], wx * wy[cy] * wz[cz] * v);
                    }
            }
        }
        if (r < e) {
            const float4 ra = binned[r];
            const unsigned ma = __float_as_uint(ra.x);
            const int y0 = (ma >> 14) & 31, z0 = (ma >> 19) & 31;
            const float v  = fmaf(vg[(((size_t)(ma & 16383)) << 5) + f], scf, shf);
            const float wx = part ? ra.y : 1.f - ra.y;
            const float wy[2] = { 1.f - ra.z, ra.z };
            const float wz[2] = { 1.f - ra.w, ra.w };
            #pragma unroll
            for (int cy = 0; cy < 2; ++cy)
                #pragma unroll
                for (int cz = 0; cz < 2; ++cz) {
                    const int yz = ((y0 + cy) << 5) + z0 + cz;
                    atomicAdd(&acc[(yz << 5) | ((f ^ yz) & 31)], wx * wy[cy] * wz[cz] * v);
                }
        }
    }
    __syncthreads();

    // write out: out[(g*F + f)*G3 + plane*1024 + yz], coalesced in yz
    float* og = out + ((size_t)g << 20) + (plane << 10);
    #pragma unroll
    for (int i = 0; i < 64; ++i) {
        const int lin = t + (i << 9);
        const int ff = lin >> 10;
        const int yz = lin & 1023;
        og[((size_t)ff << 15) + yz] = acc[(yz << 5) | ((ff ^ yz) & 31)];
    }
}

// ---------------- Fallback: direct-layout scatter (if ws too small) ----------------
__global__ __launch_bounds__(256) void scatter_kernel(
    const float* __restrict__ vals, const float* __restrict__ keys,
    const float* __restrict__ orig, const float* __restrict__ Rm,
    const float* __restrict__ tv, const float* __restrict__ scale,
    const float* __restrict__ shift, float* __restrict__ out)
{
    const int bid   = blockIdx.x;
    const int g     = bid >> 5;
    const int chunk = bid & 31;
    const int b     = g >> 2;
    const int h     = g & 3;

    __shared__ float sc[32], sh[32], sR[9], st3[3], ksc[3], ksh[3];
    const int t = threadIdx.x;
    if (t < 32)      { sc[t] = scale[12 + h * 32 + t]; sh[t] = shift[12 + h * 32 + t]; }
    else if (t < 41) { sR[t - 32]  = Rm[h * 9 + (t - 32)]; }
    else if (t < 44) { st3[t - 41] = tv[h * 3 + (t - 41)]; }
    else if (t < 47) { ksc[t - 44] = scale[h * 3 + (t - 44)];
                       ksh[t - 44] = shift[h * 3 + (t - 44)]; }
    __syncthreads();

    float* const og = out + ((size_t)g << 20);

    #pragma unroll
    for (int pp = 0; pp < 2; ++pp) {
        const int n = (chunk << 9) + (pp << 8) + t;

        const float k0 = fmaf(keys[(size_t)(g * 3 + 0) * Nn + n], ksc[0], ksh[0]);
        const float k1 = fmaf(keys[(size_t)(g * 3 + 1) * Nn + n], ksc[1], ksh[1]);
        const float k2 = fmaf(keys[(size_t)(g * 3 + 2) * Nn + n], ksc[2], ksh[2]);
        const float p0 = orig[(size_t)(b * 3 + 0) * Nn + n] + k0;
        const float p1 = orig[(size_t)(b * 3 + 1) * Nn + n] + k1;
        const float p2 = orig[(size_t)(b * 3 + 2) * Nn + n] + k2;

        int   idx[3];
        float loc[3];
        #pragma unroll
        for (int d = 0; d < 3; ++d) {
            const float tk = fmaf(sR[d*3+0], p0, fmaf(sR[d*3+1], p1, fmaf(sR[d*3+2], p2, st3[d])));
            const float la = tanhf(tk);
            const float po = (la + 1.f) * 15.5f;
            float fi = floorf(po);
            fi = fminf(fmaxf(fi, 0.f), 30.f);
            idx[d] = (int)fi;
            loc[d] = po - fi;
        }
        const int cell = (idx[0] * Gg + idx[1]) * Gg + idx[2];

        float v[32];
        const float4* vp = reinterpret_cast<const float4*>(vals + ((size_t)g * Nn + n) * Ff);
        #pragma unroll
        for (int q = 0; q < 8; ++q) {
            const float4 x = vp[q];
            v[4*q+0] = fmaf(x.x, sc[4*q+0], sh[4*q+0]);
            v[4*q+1] = fmaf(x.y, sc[4*q+1], sh[4*q+1]);
            v[4*q+2] = fmaf(x.z, sc[4*q+2], sh[4*q+2]);
            v[4*q+3] = fmaf(x.w, sc[4*q+3], sh[4*q+3]);
        }

        const float wx1 = loc[0], wx0 = 1.f - loc[0];
        const float wy1 = loc[1], wy0 = 1.f - loc[1];
        const float wz1 = loc[2], wz0 = 1.f - loc[2];
        const float cw[8] = { wx0*wy0*wz0, wx0*wy0*wz1, wx0*wy1*wz0, wx0*wy1*wz1,
                              wx1*wy0*wz0, wx1*wy0*wz1, wx1*wy1*wz0, wx1*wy1*wz1 };
        const int  co[8] = { 0, 1, 32, 33, 1024, 1025, 1056, 1057 };

        #pragma unroll
        for (int ff = 0; ff < 32; ++ff) {
            float* const pf = og + (size_t)ff * G3v + cell;
            const float vf = v[ff];
            #pragma unroll
            for (int c8 = 0; c8 < 8; ++c8) {
                atomicAdd(pf + co[c8], cw[c8] * vf);
            }
        }
    }
}

extern "C" void kernel_launch(void* const* d_in, const int* in_sizes, int n_in,
                              void* d_out, int out_size, void* d_ws, size_t ws_size,
                              hipStream_t stream)
{
    const float* X    = (const float*)d_in[0];
    const float* orig = (const float*)d_in[1];
    const float* W    = (const float*)d_in[2];
    const float* kg   = (const float*)d_in[3];
    const float* kb   = (const float*)d_in[4];
    const float* vg   = (const float*)d_in[5];
    const float* vb   = (const float*)d_in[6];
    const float* Rm   = (const float*)d_in[7];
    const float* tv   = (const float*)d_in[8];
    float* out = (float*)d_out;
    float* ws  = (float*)d_ws;

    // float offsets in ws
    float* vals  = ws;                     // 16,777,216
    float* keys  = ws + 16777216;          //  1,572,864
    float* gsum  = ws + 18350080;          // 140
    float* gsq   = gsum + 140;
    float* scale = gsum + 280;
    float* shift = scale + 140;
    int*   cnt    = (int*)(ws + 18350848); // 992
    int*   basep  = (int*)(ws + 18351872); // 992
    int*   cursor = (int*)(ws + 18352896); // 992
    float4* rec    = (float4*)(ws + 18354176); // 524288 float4 = 2,097,152 f
    float4* binned = (float4*)(ws + 20451328); // 524288 float4
    const size_t need_bytes = (size_t)22548480 * sizeof(float);   // ~90.2 MiB

    hipMemsetAsync(gsum, 0, 280 * sizeof(float), stream);

    gemm_stats_kernel<<<2048, 256, 0, stream>>>(X, W, vals, keys, gsum, gsq);
    finalize_kernel<<<1, 256, 0, stream>>>(gsum, gsq, kg, kb, vg, vb, scale, shift);

    if (ws_size >= need_bytes) {
        hipMemsetAsync(cnt, 0, 992 * sizeof(int), stream);
        points_kernel<<<2048, 256, 0, stream>>>(keys, orig, Rm, tv, scale, shift, rec, cnt);
        scan_kernel<<<1, 1024, 0, stream>>>(cnt, basep, cursor);
        fill_kernel<<<2048, 256, 0, stream>>>(rec, cursor, binned);
        plane_kernel<<<1024, 512, 0, stream>>>(vals, binned, basep, cnt, scale, shift, out);
    } else {
        hipMemsetAsync(out, 0, (size_t)out_size * sizeof(float), stream);
        scatter_kernel<<<1024, 256, 0, stream>>>(vals, keys, orig, Rm, tv, scale, shift, out);
    }
}

// Round 4
// 1381.929 us; speedup vs baseline: 1.3824x; 1.3824x over previous
//
#include <hip/hip_runtime.h>
#include <cstddef>

#define Bz 8
#define Nn 16384
#define MD 256
#define Ff 32
#define Hh 4
#define Gg 32
#define G3v 32768
#define CKV 140
#define NG 32          // B*H groups
#define NBIN 31        // x0 bins per group (x0 in [0,30])

// ---------------- Pass 1: kv = W·X (per batch), fused BN statistics ----------------
__global__ __launch_bounds__(256) void gemm_stats_kernel(
    const float* __restrict__ X, const float* __restrict__ W,
    float* __restrict__ vals, float* __restrict__ keys,
    float* __restrict__ gsum, float* __restrict__ gsq)
{
    __shared__ float Xs[64][64];
    __shared__ float Ws[64][161];
    __shared__ float red[280];

    const int bid = blockIdx.x;
    const int b   = bid >> 8;
    const int n0  = (bid & 255) << 6;
    const int t   = threadIdx.x;
    const int tx  = t & 31;
    const int ty  = t >> 5;

    float acc[5][8];
    #pragma unroll
    for (int i = 0; i < 5; ++i)
        #pragma unroll
        for (int j = 0; j < 8; ++j) acc[i][j] = 0.f;

    for (int k0 = 0; k0 < MD; k0 += 64) {
        {
            const int r  = t >> 4;
            const int c4 = (t & 15) << 2;
            #pragma unroll
            for (int i = 0; i < 4; ++i) {
                const int k = r + i * 16;
                const float4 v = *reinterpret_cast<const float4*>(
                    X + (size_t)(b * MD + k0 + k) * Nn + n0 + c4);
                *reinterpret_cast<float4*>(&Xs[k][c4]) = v;
            }
        }
        for (int idx = t; idx < 64 * 160; idx += 256) {
            const int c = idx >> 6;
            const int k = idx & 63;
            Ws[k][c] = (c < CKV) ? W[c * MD + k0 + k] : 0.f;
        }
        __syncthreads();

        for (int k = 0; k < 64; ++k) {
            float xv[8];
            *reinterpret_cast<float4*>(&xv[0]) = *reinterpret_cast<const float4*>(&Xs[k][ty * 8]);
            *reinterpret_cast<float4*>(&xv[4]) = *reinterpret_cast<const float4*>(&Xs[k][ty * 8 + 4]);
            const float w0 = Ws[k][tx];
            const float w1 = Ws[k][tx + 32];
            const float w2 = Ws[k][tx + 64];
            const float w3 = Ws[k][tx + 96];
            const float w4 = Ws[k][tx + 128];
            #pragma unroll
            for (int j = 0; j < 8; ++j) {
                acc[0][j] = fmaf(w0, xv[j], acc[0][j]);
                acc[1][j] = fmaf(w1, xv[j], acc[1][j]);
                acc[2][j] = fmaf(w2, xv[j], acc[2][j]);
                acc[3][j] = fmaf(w3, xv[j], acc[3][j]);
                acc[4][j] = fmaf(w4, xv[j], acc[4][j]);
            }
        }
        __syncthreads();
    }

    const int nb = n0 + ty * 8;
    #pragma unroll
    for (int cg = 0; cg < 5; ++cg) {
        const int c = tx + 32 * cg;
        if (c >= CKV) continue;
        if (c < 12) {
            const int hh = c / 3, kk = c - (c / 3) * 3;
            float* dst = keys + (size_t)((b * Hh + hh) * 3 + kk) * Nn + nb;
            #pragma unroll
            for (int j = 0; j < 8; ++j) dst[j] = acc[cg][j];
        } else {
            const int cv = c - 12;
            const int hh = cv >> 5, f = cv & 31;
            float* dst = vals + ((size_t)(b * Hh + hh) * Nn + nb) * Ff + f;
            #pragma unroll
            for (int j = 0; j < 8; ++j) dst[(size_t)j * Ff] = acc[cg][j];
        }
    }

    red[t] = 0.f;
    if (t < 24) red[256 + t] = 0.f;
    __syncthreads();
    #pragma unroll
    for (int cg = 0; cg < 5; ++cg) {
        const int c = tx + 32 * cg;
        if (c >= CKV) continue;
        float s = 0.f, q = 0.f;
        #pragma unroll
        for (int j = 0; j < 8; ++j) { s += acc[cg][j]; q = fmaf(acc[cg][j], acc[cg][j], q); }
        atomicAdd(&red[c], s);
        atomicAdd(&red[140 + c], q);
    }
    __syncthreads();
    if (t < CKV) {
        atomicAdd(&gsum[t], red[t]);
        atomicAdd(&gsq[t],  red[140 + t]);
    }
}

// ---------------- Pass 2: finalize BN affine params ----------------
__global__ void finalize_kernel(const float* __restrict__ gsum, const float* __restrict__ gsq,
                                const float* __restrict__ kg, const float* __restrict__ kb,
                                const float* __restrict__ vg, const float* __restrict__ vb,
                                float* __restrict__ scale, float* __restrict__ shift)
{
    const int c = threadIdx.x;
    if (c < CKV) {
        const float inv = 1.f / (float)(Bz * Nn);
        const float m = gsum[c] * inv;
        const float v = fmaf(-m, m, gsq[c] * inv);
        float ga, be;
        if (c < 12) { ga = kg[c]; be = kb[c]; }
        else        { ga = vg[c - 12]; be = vb[c - 12]; }
        const float sc = ga * rsqrtf(v + 1e-5f);
        scale[c] = sc;
        shift[c] = fmaf(-m, sc, be);
    }
}

// ---------------- Pass 3a: per-point transform -> record + bin histogram ----------------
__global__ __launch_bounds__(256) void points_kernel(
    const float* __restrict__ keys, const float* __restrict__ orig,
    const float* __restrict__ Rm, const float* __restrict__ tv,
    const float* __restrict__ scale, const float* __restrict__ shift,
    float4* __restrict__ rec, int* __restrict__ cnt)
{
    const int bid = blockIdx.x;
    const int g   = bid >> 6;
    const int b   = g >> 2;
    const int h   = g & 3;
    const int t   = threadIdx.x;
    const int n   = ((bid & 63) << 8) + t;

    __shared__ float sR[9], st3[3], ksc[3], ksh[3];
    if (t < 9)       sR[t] = Rm[h * 9 + t];
    else if (t < 12) st3[t - 9] = tv[h * 3 + (t - 9)];
    else if (t < 15) { ksc[t - 12] = scale[h * 3 + (t - 12)];
                       ksh[t - 12] = shift[h * 3 + (t - 12)]; }
    __syncthreads();

    const float k0 = fmaf(keys[(size_t)(g * 3 + 0) * Nn + n], ksc[0], ksh[0]);
    const float k1 = fmaf(keys[(size_t)(g * 3 + 1) * Nn + n], ksc[1], ksh[1]);
    const float k2 = fmaf(keys[(size_t)(g * 3 + 2) * Nn + n], ksc[2], ksh[2]);
    const float p0 = orig[(size_t)(b * 3 + 0) * Nn + n] + k0;
    const float p1 = orig[(size_t)(b * 3 + 1) * Nn + n] + k1;
    const float p2 = orig[(size_t)(b * 3 + 2) * Nn + n] + k2;

    int   idx[3];
    float loc[3];
    #pragma unroll
    for (int d = 0; d < 3; ++d) {
        const float tk = fmaf(sR[d*3+0], p0, fmaf(sR[d*3+1], p1, fmaf(sR[d*3+2], p2, st3[d])));
        const float la = tanhf(tk);
        const float po = (la + 1.f) * 15.5f;
        float fi = floorf(po);
        fi = fminf(fmaxf(fi, 0.f), 30.f);
        idx[d] = (int)fi;
        loc[d] = po - fi;
    }

    const unsigned meta = (unsigned)n | ((unsigned)idx[1] << 14) |
                          ((unsigned)idx[2] << 19) | ((unsigned)idx[0] << 24);
    float4 r;
    r.x = __uint_as_float(meta);
    r.y = loc[0]; r.z = loc[1]; r.w = loc[2];
    rec[(size_t)g * Nn + n] = r;
    atomicAdd(&cnt[g * NBIN + idx[0]], 1);
}

// ---------------- Pass 3b: exclusive scan over 992 bins ----------------
__global__ void scan_kernel(const int* __restrict__ cnt,
                            int* __restrict__ base, int* __restrict__ cursor)
{
    __shared__ int s[1024];
    const int t = threadIdx.x;   // 1024 threads
    const int own = (t < NG * NBIN) ? cnt[t] : 0;
    s[t] = own;
    __syncthreads();
    for (int off = 1; off < 1024; off <<= 1) {
        const int x = (t >= off) ? s[t - off] : 0;
        __syncthreads();
        s[t] += x;
        __syncthreads();
    }
    if (t < NG * NBIN) {
        const int e = s[t] - own;   // exclusive
        base[t] = e;
        cursor[t] = e;
    }
}

// ---------------- Pass 3c: counting-sort records into bins ----------------
__global__ __launch_bounds__(256) void fill_kernel(
    const float4* __restrict__ rec, int* __restrict__ cursor,
    float4* __restrict__ binned)
{
    const int bid = blockIdx.x;
    const int g   = bid >> 6;
    const int t   = threadIdx.x;
    const int n   = ((bid & 63) << 8) + t;
    const float4 r = rec[(size_t)g * Nn + n];
    const unsigned meta = __float_as_uint(r.x);
    const int x0 = (meta >> 24) & 31;
    const int pos = atomicAdd(&cursor[g * NBIN + x0], 1);
    binned[pos] = r;
}

// ---------------- Pass 3d: per-plane LDS accumulate + direct write-out ----------------
// Grid: 1024 blocks, plane-major: g = bid&31, plane = bid>>5.
// 1024 threads = 32 groups x 32 lanes; LDS 128 KiB plane [yz][f^yz] swizzled.
__global__ __launch_bounds__(1024) void plane_kernel(
    const float* __restrict__ vals, const float4* __restrict__ binned,
    const int* __restrict__ base, const int* __restrict__ cnt,
    const float* __restrict__ scale, const float* __restrict__ shift,
    float* __restrict__ out)
{
    __shared__ float acc[32768];
    __shared__ float sscale[32], sshift[32];

    const int bid   = blockIdx.x;
    const int g     = bid & 31;
    const int plane = bid >> 5;
    const int h     = g & 3;
    const int t     = threadIdx.x;

    for (int i = t; i < 32768; i += 1024) acc[i] = 0.f;
    if (t < 32) { sscale[t] = scale[12 + h * 32 + t]; sshift[t] = shift[12 + h * 32 + t]; }
    __syncthreads();

    const int f   = t & 31;
    const int grp = t >> 5;      // 32 groups
    const float scf = sscale[f], shf = sshift[f];
    const float* vg = vals + ((size_t)g << 19);   // g * Nn * Ff

    #pragma unroll
    for (int part = 0; part < 2; ++part) {
        const int x0 = plane - part;
        if (x0 < 0 || x0 > 30) continue;
        const int bin = g * NBIN + x0;
        const int s = base[bin];
        const int e = s + cnt[bin];

        int r = s + grp;
        for (; r + 32 < e; r += 64) {
            const float4 ra = binned[r];
            const float4 rb = binned[r + 32];
            const unsigned ma = __float_as_uint(ra.x);
            const unsigned mb = __float_as_uint(rb.x);
            const float va = vg[(((size_t)(ma & 16383)) << 5) + f];
            const float vb = vg[(((size_t)(mb & 16383)) << 5) + f];

            {
                const int y0 = (ma >> 14) & 31, z0 = (ma >> 19) & 31;
                const float v  = fmaf(va, scf, shf);
                const float wx = part ? ra.y : 1.f - ra.y;
                const float wy[2] = { 1.f - ra.z, ra.z };
                const float wz[2] = { 1.f - ra.w, ra.w };
                #pragma unroll
                for (int cy = 0; cy < 2; ++cy)
                    #pragma unroll
                    for (int cz = 0; cz < 2; ++cz) {
                        const int yz = ((y0 + cy) << 5) + z0 + cz;
                        unsafeAtomicAdd(&acc[(yz << 5) | ((f ^ yz) & 31)], wx * wy[cy] * wz[cz] * v);
                    }
            }
            {
                const int y0 = (mb >> 14) & 31, z0 = (mb >> 19) & 31;
                const float v  = fmaf(vb, scf, shf);
                const float wx = part ? rb.y : 1.f - rb.y;
                const float wy[2] = { 1.f - rb.z, rb.z };
                const float wz[2] = { 1.f - rb.w, rb.w };
                #pragma unroll
                for (int cy = 0; cy < 2; ++cy)
                    #pragma unroll
                    for (int cz = 0; cz < 2; ++cz) {
                        const int yz = ((y0 + cy) << 5) + z0 + cz;
                        unsafeAtomicAdd(&acc[(yz << 5) | ((f ^ yz) & 31)], wx * wy[cy] * wz[cz] * v);
                    }
            }
        }
        if (r < e) {
            const float4 ra = binned[r];
            const unsigned ma = __float_as_uint(ra.x);
            const int y0 = (ma >> 14) & 31, z0 = (ma >> 19) & 31;
            const float v  = fmaf(vg[(((size_t)(ma & 16383)) << 5) + f], scf, shf);
            const float wx = part ? ra.y : 1.f - ra.y;
            const float wy[2] = { 1.f - ra.z, ra.z };
            const float wz[2] = { 1.f - ra.w, ra.w };
            #pragma unroll
            for (int cy = 0; cy < 2; ++cy)
                #pragma unroll
                for (int cz = 0; cz < 2; ++cz) {
                    const int yz = ((y0 + cy) << 5) + z0 + cz;
                    unsafeAtomicAdd(&acc[(yz << 5) | ((f ^ yz) & 31)], wx * wy[cy] * wz[cz] * v);
                }
        }
    }
    __syncthreads();

    // write out: out[(g*F + ff)*G3 + plane*1024 + yz]; iteration i -> ff=i, yz=t
    float* og = out + ((size_t)g << 20) + (plane << 10);
    #pragma unroll
    for (int i = 0; i < 32; ++i) {
        og[((size_t)i << 15) + t] = acc[(t << 5) | ((i ^ t) & 31)];
    }
}

// ---------------- Fallback: direct-layout scatter (if ws too small) ----------------
__global__ __launch_bounds__(256) void scatter_kernel(
    const float* __restrict__ vals, const float* __restrict__ keys,
    const float* __restrict__ orig, const float* __restrict__ Rm,
    const float* __restrict__ tv, const float* __restrict__ scale,
    const float* __restrict__ shift, float* __restrict__ out)
{
    const int bid   = blockIdx.x;
    const int g     = bid >> 5;
    const int chunk = bid & 31;
    const int b     = g >> 2;
    const int h     = g & 3;

    __shared__ float sc[32], sh[32], sR[9], st3[3], ksc[3], ksh[3];
    const int t = threadIdx.x;
    if (t < 32)      { sc[t] = scale[12 + h * 32 + t]; sh[t] = shift[12 + h * 32 + t]; }
    else if (t < 41) { sR[t - 32]  = Rm[h * 9 + (t - 32)]; }
    else if (t < 44) { st3[t - 41] = tv[h * 3 + (t - 41)]; }
    else if (t < 47) { ksc[t - 44] = scale[h * 3 + (t - 44)];
                       ksh[t - 44] = shift[h * 3 + (t - 44)]; }
    __syncthreads();

    float* const og = out + ((size_t)g << 20);

    #pragma unroll
    for (int pp = 0; pp < 2; ++pp) {
        const int n = (chunk << 9) + (pp << 8) + t;

        const float k0 = fmaf(keys[(size_t)(g * 3 + 0) * Nn + n], ksc[0], ksh[0]);
        const float k1 = fmaf(keys[(size_t)(g * 3 + 1) * Nn + n], ksc[1], ksh[1]);
        const float k2 = fmaf(keys[(size_t)(g * 3 + 2) * Nn + n], ksc[2], ksh[2]);
        const float p0 = orig[(size_t)(b * 3 + 0) * Nn + n] + k0;
        const float p1 = orig[(size_t)(b * 3 + 1) * Nn + n] + k1;
        const float p2 = orig[(size_t)(b * 3 + 2) * Nn + n] + k2;

        int   idx[3];
        float loc[3];
        #pragma unroll
        for (int d = 0; d < 3; ++d) {
            const float tk = fmaf(sR[d*3+0], p0, fmaf(sR[d*3+1], p1, fmaf(sR[d*3+2], p2, st3[d])));
            const float la = tanhf(tk);
            const float po = (la + 1.f) * 15.5f;
            float fi = floorf(po);
            fi = fminf(fmaxf(fi, 0.f), 30.f);
            idx[d] = (int)fi;
            loc[d] = po - fi;
        }
        const int cell = (idx[0] * Gg + idx[1]) * Gg + idx[2];

        float v[32];
        const float4* vp = reinterpret_cast<const float4*>(vals + ((size_t)g * Nn + n) * Ff);
        #pragma unroll
        for (int q = 0; q < 8; ++q) {
            const float4 x = vp[q];
            v[4*q+0] = fmaf(x.x, sc[4*q+0], sh[4*q+0]);
            v[4*q+1] = fmaf(x.y, sc[4*q+1], sh[4*q+1]);
            v[4*q+2] = fmaf(x.z, sc[4*q+2], sh[4*q+2]);
            v[4*q+3] = fmaf(x.w, sc[4*q+3], sh[4*q+3]);
        }

        const float wx1 = loc[0], wx0 = 1.f - loc[0];
        const float wy1 = loc[1], wy0 = 1.f - loc[1];
        const float wz1 = loc[2], wz0 = 1.f - loc[2];
        const float cw[8] = { wx0*wy0*wz0, wx0*wy0*wz1, wx0*wy1*wz0, wx0*wy1*wz1,
                              wx1*wy0*wz0, wx1*wy0*wz1, wx1*wy1*wz0, wx1*wy1*wz1 };
        const int  co[8] = { 0, 1, 32, 33, 1024, 1025, 1056, 1057 };

        #pragma unroll
        for (int ff = 0; ff < 32; ++ff) {
            float* const pf = og + (size_t)ff * G3v + cell;
            const float vf = v[ff];
            #pragma unroll
            for (int c8 = 0; c8 < 8; ++c8) {
                atomicAdd(pf + co[c8], cw[c8] * vf);
            }
        }
    }
}

extern "C" void kernel_launch(void* const* d_in, const int* in_sizes, int n_in,
                              void* d_out, int out_size, void* d_ws, size_t ws_size,
                              hipStream_t stream)
{
    const float* X    = (const float*)d_in[0];
    const float* orig = (const float*)d_in[1];
    const float* W    = (const float*)d_in[2];
    const float* kg   = (const float*)d_in[3];
    const float* kb   = (const float*)d_in[4];
    const float* vg   = (const float*)d_in[5];
    const float* vb   = (const float*)d_in[6];
    const float* Rm   = (const float*)d_in[7];
    const float* tv   = (const float*)d_in[8];
    float* out = (float*)d_out;
    float* ws  = (float*)d_ws;

    float* vals  = ws;                     // 16,777,216
    float* keys  = ws + 16777216;          //  1,572,864
    float* gsum  = ws + 18350080;          // 140
    float* gsq   = gsum + 140;
    float* scale = gsum + 280;
    float* shift = scale + 140;
    int*   cnt    = (int*)(ws + 18350848); // 992
    int*   basep  = (int*)(ws + 18351872); // 992
    int*   cursor = (int*)(ws + 18352896); // 992
    float4* rec    = (float4*)(ws + 18354176); // 524288 float4
    float4* binned = (float4*)(ws + 20451328); // 524288 float4
    const size_t need_bytes = (size_t)22548480 * sizeof(float);

    hipMemsetAsync(gsum, 0, 280 * sizeof(float), stream);

    gemm_stats_kernel<<<2048, 256, 0, stream>>>(X, W, vals, keys, gsum, gsq);
    finalize_kernel<<<1, 256, 0, stream>>>(gsum, gsq, kg, kb, vg, vb, scale, shift);

    if (ws_size >= need_bytes) {
        hipMemsetAsync(cnt, 0, 992 * sizeof(int), stream);
        points_kernel<<<2048, 256, 0, stream>>>(keys, orig, Rm, tv, scale, shift, rec, cnt);
        scan_kernel<<<1, 1024, 0, stream>>>(cnt, basep, cursor);
        fill_kernel<<<2048, 256, 0, stream>>>(rec, cursor, binned);
        plane_kernel<<<1024, 1024, 0, stream>>>(vals, binned, basep, cnt, scale, shift, out);
    } else {
        hipMemsetAsync(out, 0, (size_t)out_size * sizeof(float), stream);
        scatter_kernel<<<1024, 256, 0, stream>>>(vals, keys, orig, Rm, tv, scale, shift, out);
    }
}

// Round 5
// 648.759 us; speedup vs baseline: 2.9446x; 2.1301x over previous
//
#include <hip/hip_runtime.h>
#include <cstddef>

#define Bz 8
#define Nn 16384
#define MD 256
#define Ff 32
#define Hh 4
#define Gg 32
#define G3v 32768
#define CKV 140
#define NG 32            // B*H groups
#define NBX 31           // x0 in [0,30]
#define NBY 31           // y0 in [0,30]
#define NBINS (NG*NBX*NBY)   // 30752

// ---------------- Pass 1: kv = W·X (per batch), fused BN statistics ----------------
__global__ __launch_bounds__(256) void gemm_stats_kernel(
    const float* __restrict__ X, const float* __restrict__ W,
    float* __restrict__ vals, float* __restrict__ keys,
    float* __restrict__ gsum, float* __restrict__ gsq)
{
    __shared__ float Xs[64][64];
    __shared__ float Ws[64][161];
    __shared__ float red[280];

    const int bid = blockIdx.x;
    const int b   = bid >> 8;
    const int n0  = (bid & 255) << 6;
    const int t   = threadIdx.x;
    const int tx  = t & 31;
    const int ty  = t >> 5;

    float acc[5][8];
    #pragma unroll
    for (int i = 0; i < 5; ++i)
        #pragma unroll
        for (int j = 0; j < 8; ++j) acc[i][j] = 0.f;

    for (int k0 = 0; k0 < MD; k0 += 64) {
        {
            const int r  = t >> 4;
            const int c4 = (t & 15) << 2;
            #pragma unroll
            for (int i = 0; i < 4; ++i) {
                const int k = r + i * 16;
                const float4 v = *reinterpret_cast<const float4*>(
                    X + (size_t)(b * MD + k0 + k) * Nn + n0 + c4);
                *reinterpret_cast<float4*>(&Xs[k][c4]) = v;
            }
        }
        for (int idx = t; idx < 64 * 160; idx += 256) {
            const int c = idx >> 6;
            const int k = idx & 63;
            Ws[k][c] = (c < CKV) ? W[c * MD + k0 + k] : 0.f;
        }
        __syncthreads();

        for (int k = 0; k < 64; ++k) {
            float xv[8];
            *reinterpret_cast<float4*>(&xv[0]) = *reinterpret_cast<const float4*>(&Xs[k][ty * 8]);
            *reinterpret_cast<float4*>(&xv[4]) = *reinterpret_cast<const float4*>(&Xs[k][ty * 8 + 4]);
            const float w0 = Ws[k][tx];
            const float w1 = Ws[k][tx + 32];
            const float w2 = Ws[k][tx + 64];
            const float w3 = Ws[k][tx + 96];
            const float w4 = Ws[k][tx + 128];
            #pragma unroll
            for (int j = 0; j < 8; ++j) {
                acc[0][j] = fmaf(w0, xv[j], acc[0][j]);
                acc[1][j] = fmaf(w1, xv[j], acc[1][j]);
                acc[2][j] = fmaf(w2, xv[j], acc[2][j]);
                acc[3][j] = fmaf(w3, xv[j], acc[3][j]);
                acc[4][j] = fmaf(w4, xv[j], acc[4][j]);
            }
        }
        __syncthreads();
    }

    const int nb = n0 + ty * 8;
    #pragma unroll
    for (int cg = 0; cg < 5; ++cg) {
        const int c = tx + 32 * cg;
        if (c >= CKV) continue;
        if (c < 12) {
            const int hh = c / 3, kk = c - (c / 3) * 3;
            float* dst = keys + (size_t)((b * Hh + hh) * 3 + kk) * Nn + nb;
            #pragma unroll
            for (int j = 0; j < 8; ++j) dst[j] = acc[cg][j];
        } else {
            const int cv = c - 12;
            const int hh = cv >> 5, f = cv & 31;
            float* dst = vals + ((size_t)(b * Hh + hh) * Nn + nb) * Ff + f;
            #pragma unroll
            for (int j = 0; j < 8; ++j) dst[(size_t)j * Ff] = acc[cg][j];
        }
    }

    red[t] = 0.f;
    if (t < 24) red[256 + t] = 0.f;
    __syncthreads();
    #pragma unroll
    for (int cg = 0; cg < 5; ++cg) {
        const int c = tx + 32 * cg;
        if (c >= CKV) continue;
        float s = 0.f, q = 0.f;
        #pragma unroll
        for (int j = 0; j < 8; ++j) { s += acc[cg][j]; q = fmaf(acc[cg][j], acc[cg][j], q); }
        atomicAdd(&red[c], s);
        atomicAdd(&red[140 + c], q);
    }
    __syncthreads();
    if (t < CKV) {
        atomicAdd(&gsum[t], red[t]);
        atomicAdd(&gsq[t],  red[140 + t]);
    }
}

// ---------------- Pass 2: finalize BN affine params ----------------
__global__ void finalize_kernel(const float* __restrict__ gsum, const float* __restrict__ gsq,
                                const float* __restrict__ kg, const float* __restrict__ kb,
                                const float* __restrict__ vg, const float* __restrict__ vb,
                                float* __restrict__ scale, float* __restrict__ shift)
{
    const int c = threadIdx.x;
    if (c < CKV) {
        const float inv = 1.f / (float)(Bz * Nn);
        const float m = gsum[c] * inv;
        const float v = fmaf(-m, m, gsq[c] * inv);
        float ga, be;
        if (c < 12) { ga = kg[c]; be = kb[c]; }
        else        { ga = vg[c - 12]; be = vb[c - 12]; }
        const float sc = ga * rsqrtf(v + 1e-5f);
        scale[c] = sc;
        shift[c] = fmaf(-m, sc, be);
    }
}

// ---------------- Pass 3a: per-point transform -> record + (g,x0,y0) histogram ----------------
// meta = n | z0<<14 | y0<<19 | x0<<24
__global__ __launch_bounds__(256) void points_kernel(
    const float* __restrict__ keys, const float* __restrict__ orig,
    const float* __restrict__ Rm, const float* __restrict__ tv,
    const float* __restrict__ scale, const float* __restrict__ shift,
    float4* __restrict__ rec, int* __restrict__ cnt)
{
    const int bid = blockIdx.x;
    const int g   = bid >> 6;
    const int b   = g >> 2;
    const int h   = g & 3;
    const int t   = threadIdx.x;
    const int n   = ((bid & 63) << 8) + t;

    __shared__ float sR[9], st3[3], ksc[3], ksh[3];
    if (t < 9)       sR[t] = Rm[h * 9 + t];
    else if (t < 12) st3[t - 9] = tv[h * 3 + (t - 9)];
    else if (t < 15) { ksc[t - 12] = scale[h * 3 + (t - 12)];
                       ksh[t - 12] = shift[h * 3 + (t - 12)]; }
    __syncthreads();

    const float k0 = fmaf(keys[(size_t)(g * 3 + 0) * Nn + n], ksc[0], ksh[0]);
    const float k1 = fmaf(keys[(size_t)(g * 3 + 1) * Nn + n], ksc[1], ksh[1]);
    const float k2 = fmaf(keys[(size_t)(g * 3 + 2) * Nn + n], ksc[2], ksh[2]);
    const float p0 = orig[(size_t)(b * 3 + 0) * Nn + n] + k0;
    const float p1 = orig[(size_t)(b * 3 + 1) * Nn + n] + k1;
    const float p2 = orig[(size_t)(b * 3 + 2) * Nn + n] + k2;

    int   idx[3];
    float loc[3];
    #pragma unroll
    for (int d = 0; d < 3; ++d) {
        const float tk = fmaf(sR[d*3+0], p0, fmaf(sR[d*3+1], p1, fmaf(sR[d*3+2], p2, st3[d])));
        const float la = tanhf(tk);
        const float po = (la + 1.f) * 15.5f;
        float fi = floorf(po);
        fi = fminf(fmaxf(fi, 0.f), 30.f);
        idx[d] = (int)fi;
        loc[d] = po - fi;
    }

    const unsigned meta = (unsigned)n | ((unsigned)idx[2] << 14) |
                          ((unsigned)idx[1] << 19) | ((unsigned)idx[0] << 24);
    float4 r;
    r.x = __uint_as_float(meta);
    r.y = loc[0]; r.z = loc[1]; r.w = loc[2];
    rec[(size_t)g * Nn + n] = r;
    atomicAdd(&cnt[(g * NBX + idx[0]) * NBY + idx[1]], 1);
}

// ---------------- Pass 3b: exclusive scan over 30752 bins (1 block) ----------------
__global__ __launch_bounds__(1024) void scan_kernel(
    const int* __restrict__ cnt, int* __restrict__ basep, int* __restrict__ cursor)
{
    __shared__ int s[1024];
    const int t = threadIdx.x;
    int loc[32];
    int sum = 0;
    const int i0 = t << 5;
    #pragma unroll
    for (int j = 0; j < 32; ++j) {
        const int idx = i0 + j;
        const int c = (idx < NBINS) ? cnt[idx] : 0;
        loc[j] = sum; sum += c;
    }
    s[t] = sum;
    __syncthreads();
    for (int off = 1; off < 1024; off <<= 1) {
        const int xv = (t >= off) ? s[t - off] : 0;
        __syncthreads();
        s[t] += xv;
        __syncthreads();
    }
    const int off0 = s[t] - sum;   // exclusive block offset
    #pragma unroll
    for (int j = 0; j < 32; ++j) {
        const int idx = i0 + j;
        if (idx < NBINS) { const int e = off0 + loc[j]; basep[idx] = e; cursor[idx] = e; }
    }
}

// ---------------- Pass 3c: counting-sort records into (g,x0,y0) bins ----------------
__global__ __launch_bounds__(256) void fill_kernel(
    const float4* __restrict__ rec, int* __restrict__ cursor,
    float4* __restrict__ binned)
{
    const int bid = blockIdx.x;
    const int g   = bid >> 6;
    const int t   = threadIdx.x;
    const int n   = ((bid & 63) << 8) + t;
    const float4 r = rec[(size_t)g * Nn + n];
    const unsigned meta = __float_as_uint(r.x);
    const int x0 = (meta >> 24) & 31;
    const int y0 = (meta >> 19) & 31;
    const int pos = atomicAdd(&cursor[(g * NBX + x0) * NBY + y0], 1);
    binned[pos] = r;
}

// ---------------- Pass 3d: gather — no atomics anywhere ----------------
// Block = (g, x-plane): 1024 blocks; 1024 threads = 32 y-groups x 32 f-lanes.
// Each group privately owns tile[y][z][f^z] (4 KB); plain ds_read+fma+ds_write.
__global__ __launch_bounds__(1024) void gather_kernel(
    const float* __restrict__ vals, const float4* __restrict__ binned,
    const int* __restrict__ base, const int* __restrict__ cnt,
    const float* __restrict__ scale, const float* __restrict__ shift,
    float* __restrict__ out)
{
    __shared__ float tile[32768];
    __shared__ float sscale[32], sshift[32];

    const int bid = blockIdx.x;
    const int g   = bid & 31;
    const int x   = bid >> 5;
    const int h   = g & 3;
    const int t   = threadIdx.x;

    {
        const float4 z4 = make_float4(0.f, 0.f, 0.f, 0.f);
        #pragma unroll
        for (int i = 0; i < 8; ++i)
            *reinterpret_cast<float4*>(&tile[(t << 2) + (i << 12)]) = z4;
    }
    if (t < 32) { sscale[t] = scale[12 + h * 32 + t]; sshift[t] = shift[12 + h * 32 + t]; }
    __syncthreads();

    const int f = t & 31;
    const int y = t >> 5;
    const float scf = sscale[f], shf = sshift[f];
    const float* vg = vals + ((size_t)g << 19);     // g * Nn * Ff
    float* const tg = &tile[y << 10];               // this group's private 32x32 tile

    #pragma unroll
    for (int dy = 0; dy < 2; ++dy) {
        const int y0 = y - 1 + dy;                  // dy=0 -> cy=1 (weight ly); dy=1 -> cy=0
        if ((unsigned)y0 > 30u) continue;
        #pragma unroll
        for (int dx = 0; dx < 2; ++dx) {
            const int x0 = x - 1 + dx;              // dx=0 -> cx=1 (weight lx); dx=1 -> cx=0
            if ((unsigned)x0 > 30u) continue;
            const int bin = (g * NBX + x0) * NBY + y0;
            int r = base[bin];
            const int e = r + cnt[bin];
            for (; r < e; ++r) {
                const float4 ra = binned[r];        // broadcast within group
                const unsigned ma = __float_as_uint(ra.x);
                const int n  = ma & 16383;
                const int z0 = (ma >> 14) & 31;
                const float wx = dx ? (1.f - ra.y) : ra.y;
                const float wy = dy ? (1.f - ra.z) : ra.z;
                const float lz = ra.w;
                const float v  = fmaf(vg[((size_t)n << 5) + f], scf, shf);
                const float vv = wx * wy * v;
                const int a0 = (z0 << 5) + (f ^ z0);
                const int a1 = ((z0 + 1) << 5) + (f ^ (z0 + 1));
                tg[a0] += (1.f - lz) * vv;          // group-serial: race-free
                tg[a1] += lz * vv;
            }
        }
    }
    __syncthreads();

    // write out[(g*F + i)*G3 + x*1024 + t], reading swizzled tile — conflict-free
    float* og = out + ((size_t)g << 20) + (x << 10);
    const int zz = t & 31;
    const int taddr = ((t >> 5) << 10) + (zz << 5);
    #pragma unroll
    for (int i = 0; i < 32; ++i) {
        og[((size_t)i << 15) + t] = tile[taddr + (i ^ zz)];
    }
}

// ---------------- Fallback: direct-layout global-atomic scatter ----------------
__global__ __launch_bounds__(256) void scatter_kernel(
    const float* __restrict__ vals, const float* __restrict__ keys,
    const float* __restrict__ orig, const float* __restrict__ Rm,
    const float* __restrict__ tv, const float* __restrict__ scale,
    const float* __restrict__ shift, float* __restrict__ out)
{
    const int bid   = blockIdx.x;
    const int g     = bid >> 5;
    const int chunk = bid & 31;
    const int b     = g >> 2;
    const int h     = g & 3;

    __shared__ float sc[32], sh[32], sR[9], st3[3], ksc[3], ksh[3];
    const int t = threadIdx.x;
    if (t < 32)      { sc[t] = scale[12 + h * 32 + t]; sh[t] = shift[12 + h * 32 + t]; }
    else if (t < 41) { sR[t - 32]  = Rm[h * 9 + (t - 32)]; }
    else if (t < 44) { st3[t - 41] = tv[h * 3 + (t - 41)]; }
    else if (t < 47) { ksc[t - 44] = scale[h * 3 + (t - 44)];
                       ksh[t - 44] = shift[h * 3 + (t - 44)]; }
    __syncthreads();

    float* const og = out + ((size_t)g << 20);

    #pragma unroll
    for (int pp = 0; pp < 2; ++pp) {
        const int n = (chunk << 9) + (pp << 8) + t;

        const float k0 = fmaf(keys[(size_t)(g * 3 + 0) * Nn + n], ksc[0], ksh[0]);
        const float k1 = fmaf(keys[(size_t)(g * 3 + 1) * Nn + n], ksc[1], ksh[1]);
        const float k2 = fmaf(keys[(size_t)(g * 3 + 2) * Nn + n], ksc[2], ksh[2]);
        const float p0 = orig[(size_t)(b * 3 + 0) * Nn + n] + k0;
        const float p1 = orig[(size_t)(b * 3 + 1) * Nn + n] + k1;
        const float p2 = orig[(size_t)(b * 3 + 2) * Nn + n] + k2;

        int   idx[3];
        float loc[3];
        #pragma unroll
        for (int d = 0; d < 3; ++d) {
            const float tk = fmaf(sR[d*3+0], p0, fmaf(sR[d*3+1], p1, fmaf(sR[d*3+2], p2, st3[d])));
            const float la = tanhf(tk);
            const float po = (la + 1.f) * 15.5f;
            float fi = floorf(po);
            fi = fminf(fmaxf(fi, 0.f), 30.f);
            idx[d] = (int)fi;
            loc[d] = po - fi;
        }
        const int cell = (idx[0] * Gg + idx[1]) * Gg + idx[2];

        float v[32];
        const float4* vp = reinterpret_cast<const float4*>(vals + ((size_t)g * Nn + n) * Ff);
        #pragma unroll
        for (int q = 0; q < 8; ++q) {
            const float4 xq = vp[q];
            v[4*q+0] = fmaf(xq.x, sc[4*q+0], sh[4*q+0]);
            v[4*q+1] = fmaf(xq.y, sc[4*q+1], sh[4*q+1]);
            v[4*q+2] = fmaf(xq.z, sc[4*q+2], sh[4*q+2]);
            v[4*q+3] = fmaf(xq.w, sc[4*q+3], sh[4*q+3]);
        }

        const float wx1 = loc[0], wx0 = 1.f - loc[0];
        const float wy1 = loc[1], wy0 = 1.f - loc[1];
        const float wz1 = loc[2], wz0 = 1.f - loc[2];
        const float cw[8] = { wx0*wy0*wz0, wx0*wy0*wz1, wx0*wy1*wz0, wx0*wy1*wz1,
                              wx1*wy0*wz0, wx1*wy0*wz1, wx1*wy1*wz0, wx1*wy1*wz1 };
        const int  co[8] = { 0, 1, 32, 33, 1024, 1025, 1056, 1057 };

        #pragma unroll
        for (int ff = 0; ff < 32; ++ff) {
            float* const pf = og + (size_t)ff * G3v + cell;
            const float vf = v[ff];
            #pragma unroll
            for (int c8 = 0; c8 < 8; ++c8) {
                atomicAdd(pf + co[c8], cw[c8] * vf);
            }
        }
    }
}

extern "C" void kernel_launch(void* const* d_in, const int* in_sizes, int n_in,
                              void* d_out, int out_size, void* d_ws, size_t ws_size,
                              hipStream_t stream)
{
    const float* X    = (const float*)d_in[0];
    const float* orig = (const float*)d_in[1];
    const float* W    = (const float*)d_in[2];
    const float* kg   = (const float*)d_in[3];
    const float* kb   = (const float*)d_in[4];
    const float* vg   = (const float*)d_in[5];
    const float* vb   = (const float*)d_in[6];
    const float* Rm   = (const float*)d_in[7];
    const float* tv   = (const float*)d_in[8];
    float* out = (float*)d_out;
    float* ws  = (float*)d_ws;

    // float-offset workspace layout
    float* vals  = ws;                          // 16,777,216
    float* keys  = ws + 16777216;               //  1,572,864
    float* gsum  = ws + 18350080;               // 140
    float* gsq   = gsum + 140;
    float* scale = gsum + 280;
    float* shift = scale + 140;
    int*   cnt    = (int*)(ws + 18350848);      // 30,752
    int*   basep  = (int*)(ws + 18381600);      // 30,752
    int*   cursor = (int*)(ws + 18412352);      // 30,752
    float4* rec    = (float4*)(ws + 18443104);  // 524,288 float4
    float4* binned = (float4*)(ws + 20540256);  // 524,288 float4
    const size_t need_bytes = (size_t)22637408 * sizeof(float);   // ~90.5 MiB

    hipMemsetAsync(gsum, 0, 280 * sizeof(float), stream);

    gemm_stats_kernel<<<2048, 256, 0, stream>>>(X, W, vals, keys, gsum, gsq);
    finalize_kernel<<<1, 256, 0, stream>>>(gsum, gsq, kg, kb, vg, vb, scale, shift);

    if (ws_size >= need_bytes) {
        hipMemsetAsync(cnt, 0, NBINS * sizeof(int), stream);
        points_kernel<<<2048, 256, 0, stream>>>(keys, orig, Rm, tv, scale, shift, rec, cnt);
        scan_kernel<<<1, 1024, 0, stream>>>(cnt, basep, cursor);
        fill_kernel<<<2048, 256, 0, stream>>>(rec, cursor, binned);
        gather_kernel<<<1024, 1024, 0, stream>>>(vals, binned, basep, cnt, scale, shift, out);
    } else {
        hipMemsetAsync(out, 0, (size_t)out_size * sizeof(float), stream);
        scatter_kernel<<<1024, 256, 0, stream>>>(vals, keys, orig, Rm, tv, scale, shift, out);
    }
}

// Round 6
// 538.013 us; speedup vs baseline: 3.5507x; 1.2058x over previous
//
#include <hip/hip_runtime.h>
#include <cstddef>

#define Bz 8
#define Nn 16384
#define MD 256
#define Ff 32
#define Hh 4
#define Gg 32
#define G3v 32768
#define CKV 140
#define NG 32            // B*H groups
#define NBX 31           // x0 in [0,30]
#define NBY 31           // y0 in [0,30]
#define NBINS (NG*NBX*NBY)   // 30752

// ---------------- Pass 1: kv = W·X (per batch), fused BN statistics ----------------
// Grid: 1024 blocks (8 batches x 128 n-chunks of 128), 256 threads.
// K-tile 32 (LDS ~38KB -> 4 blocks/CU); each thread: 5 channel-groups x 16 n.
__global__ __launch_bounds__(256, 4) void gemm_stats_kernel(
    const float* __restrict__ X, const float* __restrict__ W,
    float* __restrict__ vals, float* __restrict__ keys,
    float* __restrict__ gsum, float* __restrict__ gsq)
{
    __shared__ float Xs[32][128];    // 16 KB
    __shared__ float Ws[32][161];    // 20.6 KB, cols 140..159 zero pad
    __shared__ float red[280];

    const int bid = blockIdx.x;
    const int b   = bid >> 7;
    const int n0  = (bid & 127) << 7;
    const int t   = threadIdx.x;
    const int tx  = t & 31;
    const int ty  = t >> 5;          // 0..7

    float acc[5][16];
    #pragma unroll
    for (int i = 0; i < 5; ++i)
        #pragma unroll
        for (int j = 0; j < 16; ++j) acc[i][j] = 0.f;

    for (int k0 = 0; k0 < MD; k0 += 32) {
        // X tile 32k x 128n (float4, coalesced)
        {
            const int r  = t >> 5;
            const int c4 = (t & 31) << 2;
            #pragma unroll
            for (int i = 0; i < 4; ++i) {
                const int k = r + (i << 3);
                *reinterpret_cast<float4*>(&Xs[k][c4]) =
                    *reinterpret_cast<const float4*>(X + (size_t)(b * MD + k0 + k) * Nn + n0 + c4);
            }
        }
        // W tile 32k x 160c transposed
        #pragma unroll
        for (int i = 0; i < 20; ++i) {
            const int idx = t + (i << 8);
            const int c = idx >> 5;
            const int k = idx & 31;
            Ws[k][c] = (c < CKV) ? W[c * MD + k0 + k] : 0.f;
        }
        __syncthreads();

        for (int k = 0; k < 32; ++k) {
            float xv[16];
            #pragma unroll
            for (int q = 0; q < 4; ++q)
                *reinterpret_cast<float4*>(&xv[q * 4]) =
                    *reinterpret_cast<const float4*>(&Xs[k][ty * 16 + q * 4]);
            const float w0 = Ws[k][tx];
            const float w1 = Ws[k][tx + 32];
            const float w2 = Ws[k][tx + 64];
            const float w3 = Ws[k][tx + 96];
            const float w4 = Ws[k][tx + 128];   // zero for c>=140
            #pragma unroll
            for (int j = 0; j < 16; ++j) {
                acc[0][j] = fmaf(w0, xv[j], acc[0][j]);
                acc[1][j] = fmaf(w1, xv[j], acc[1][j]);
                acc[2][j] = fmaf(w2, xv[j], acc[2][j]);
                acc[3][j] = fmaf(w3, xv[j], acc[3][j]);
                acc[4][j] = fmaf(w4, xv[j], acc[4][j]);
            }
        }
        __syncthreads();
    }

    // ---- write raw kv: keys -> (B,H,3,N), vals -> (B,H,N,F) ----
    const int nb = n0 + ty * 16;
    #pragma unroll
    for (int cg = 0; cg < 5; ++cg) {
        const int c = tx + 32 * cg;
        if (c >= CKV) continue;
        if (c < 12) {
            const int hh = c / 3, kk = c - (c / 3) * 3;
            float* dst = keys + (size_t)((b * Hh + hh) * 3 + kk) * Nn + nb;
            #pragma unroll
            for (int j = 0; j < 16; ++j) dst[j] = acc[cg][j];
        } else {
            const int cv = c - 12;
            const int hh = cv >> 5, f = cv & 31;
            float* dst = vals + ((size_t)(b * Hh + hh) * Nn + nb) * Ff + f;
            #pragma unroll
            for (int j = 0; j < 16; ++j) dst[(size_t)j * Ff] = acc[cg][j];
        }
    }

    // ---- BN statistics: LDS reduce, then per-channel global atomics ----
    red[t] = 0.f;
    if (t < 24) red[256 + t] = 0.f;
    __syncthreads();
    #pragma unroll
    for (int cg = 0; cg < 5; ++cg) {
        const int c = tx + 32 * cg;
        if (c >= CKV) continue;
        float s = 0.f, q = 0.f;
        #pragma unroll
        for (int j = 0; j < 16; ++j) { s += acc[cg][j]; q = fmaf(acc[cg][j], acc[cg][j], q); }
        atomicAdd(&red[c], s);
        atomicAdd(&red[140 + c], q);
    }
    __syncthreads();
    if (t < CKV) {
        atomicAdd(&gsum[t], red[t]);
        atomicAdd(&gsq[t],  red[140 + t]);
    }
}

// ---------------- Pass 2: finalize BN affine params ----------------
__global__ void finalize_kernel(const float* __restrict__ gsum, const float* __restrict__ gsq,
                                const float* __restrict__ kg, const float* __restrict__ kb,
                                const float* __restrict__ vg, const float* __restrict__ vb,
                                float* __restrict__ scale, float* __restrict__ shift)
{
    const int c = threadIdx.x;
    if (c < CKV) {
        const float inv = 1.f / (float)(Bz * Nn);
        const float m = gsum[c] * inv;
        const float v = fmaf(-m, m, gsq[c] * inv);
        float ga, be;
        if (c < 12) { ga = kg[c]; be = kb[c]; }
        else        { ga = vg[c - 12]; be = vb[c - 12]; }
        const float sc = ga * rsqrtf(v + 1e-5f);
        scale[c] = sc;
        shift[c] = fmaf(-m, sc, be);
    }
}

// ---------------- Pass 3a: per-point transform -> record + (g,x0,y0) histogram ----------------
// meta = n | z0<<14 | y0<<19 | x0<<24
__global__ __launch_bounds__(256) void points_kernel(
    const float* __restrict__ keys, const float* __restrict__ orig,
    const float* __restrict__ Rm, const float* __restrict__ tv,
    const float* __restrict__ scale, const float* __restrict__ shift,
    float4* __restrict__ rec, int* __restrict__ cnt)
{
    const int bid = blockIdx.x;
    const int g   = bid >> 6;
    const int b   = g >> 2;
    const int h   = g & 3;
    const int t   = threadIdx.x;
    const int n   = ((bid & 63) << 8) + t;

    __shared__ float sR[9], st3[3], ksc[3], ksh[3];
    if (t < 9)       sR[t] = Rm[h * 9 + t];
    else if (t < 12) st3[t - 9] = tv[h * 3 + (t - 9)];
    else if (t < 15) { ksc[t - 12] = scale[h * 3 + (t - 12)];
                       ksh[t - 12] = shift[h * 3 + (t - 12)]; }
    __syncthreads();

    const float k0 = fmaf(keys[(size_t)(g * 3 + 0) * Nn + n], ksc[0], ksh[0]);
    const float k1 = fmaf(keys[(size_t)(g * 3 + 1) * Nn + n], ksc[1], ksh[1]);
    const float k2 = fmaf(keys[(size_t)(g * 3 + 2) * Nn + n], ksc[2], ksh[2]);
    const float p0 = orig[(size_t)(b * 3 + 0) * Nn + n] + k0;
    const float p1 = orig[(size_t)(b * 3 + 1) * Nn + n] + k1;
    const float p2 = orig[(size_t)(b * 3 + 2) * Nn + n] + k2;

    int   idx[3];
    float loc[3];
    #pragma unroll
    for (int d = 0; d < 3; ++d) {
        const float tk = fmaf(sR[d*3+0], p0, fmaf(sR[d*3+1], p1, fmaf(sR[d*3+2], p2, st3[d])));
        const float la = tanhf(tk);
        const float po = (la + 1.f) * 15.5f;
        float fi = floorf(po);
        fi = fminf(fmaxf(fi, 0.f), 30.f);
        idx[d] = (int)fi;
        loc[d] = po - fi;
    }

    const unsigned meta = (unsigned)n | ((unsigned)idx[2] << 14) |
                          ((unsigned)idx[1] << 19) | ((unsigned)idx[0] << 24);
    float4 r;
    r.x = __uint_as_float(meta);
    r.y = loc[0]; r.z = loc[1]; r.w = loc[2];
    rec[(size_t)g * Nn + n] = r;
    atomicAdd(&cnt[(g * NBX + idx[0]) * NBY + idx[1]], 1);
}

// ---------------- Pass 3b: exclusive scan over 30752 bins (1 block) ----------------
__global__ __launch_bounds__(1024) void scan_kernel(
    const int* __restrict__ cnt, int* __restrict__ basep, int* __restrict__ cursor)
{
    __shared__ int s[1024];
    const int t = threadIdx.x;
    int loc[32];
    int sum = 0;
    const int i0 = t << 5;
    #pragma unroll
    for (int j = 0; j < 32; ++j) {
        const int idx = i0 + j;
        const int c = (idx < NBINS) ? cnt[idx] : 0;
        loc[j] = sum; sum += c;
    }
    s[t] = sum;
    __syncthreads();
    for (int off = 1; off < 1024; off <<= 1) {
        const int xv = (t >= off) ? s[t - off] : 0;
        __syncthreads();
        s[t] += xv;
        __syncthreads();
    }
    const int off0 = s[t] - sum;   // exclusive block offset
    #pragma unroll
    for (int j = 0; j < 32; ++j) {
        const int idx = i0 + j;
        if (idx < NBINS) { const int e = off0 + loc[j]; basep[idx] = e; cursor[idx] = e; }
    }
}

// ---------------- Pass 3c: counting-sort records into (g,x0,y0) bins ----------------
__global__ __launch_bounds__(256) void fill_kernel(
    const float4* __restrict__ rec, int* __restrict__ cursor,
    float4* __restrict__ binned)
{
    const int bid = blockIdx.x;
    const int g   = bid >> 6;
    const int t   = threadIdx.x;
    const int n   = ((bid & 63) << 8) + t;
    const float4 r = rec[(size_t)g * Nn + n];
    const unsigned meta = __float_as_uint(r.x);
    const int x0 = (meta >> 24) & 31;
    const int y0 = (meta >> 19) & 31;
    const int pos = atomicAdd(&cursor[(g * NBX + x0) * NBY + y0], 1);
    binned[pos] = r;
}

// ---------------- Pass 3d: gather — no atomics anywhere ----------------
// Block = (g, x-plane): 1024 blocks; 1024 threads = 32 y-groups x 32 f-lanes.
// Each group privately owns tile[y][z][f^z] (4 KB); plain ds_read+fma+ds_write.
__global__ __launch_bounds__(1024) void gather_kernel(
    const float* __restrict__ vals, const float4* __restrict__ binned,
    const int* __restrict__ base, const int* __restrict__ cnt,
    const float* __restrict__ scale, const float* __restrict__ shift,
    float* __restrict__ out)
{
    __shared__ float tile[32768];
    __shared__ float sscale[32], sshift[32];

    const int bid = blockIdx.x;
    const int g   = bid & 31;
    const int x   = bid >> 5;
    const int h   = g & 3;
    const int t   = threadIdx.x;

    {
        const float4 z4 = make_float4(0.f, 0.f, 0.f, 0.f);
        #pragma unroll
        for (int i = 0; i < 8; ++i)
            *reinterpret_cast<float4*>(&tile[(t << 2) + (i << 12)]) = z4;
    }
    if (t < 32) { sscale[t] = scale[12 + h * 32 + t]; sshift[t] = shift[12 + h * 32 + t]; }
    __syncthreads();

    const int f = t & 31;
    const int y = t >> 5;
    const float scf = sscale[f], shf = sshift[f];
    const float* vg = vals + ((size_t)g << 19);     // g * Nn * Ff
    float* const tg = &tile[y << 10];               // this group's private 32x32 tile

    #pragma unroll
    for (int dy = 0; dy < 2; ++dy) {
        const int y0 = y - 1 + dy;                  // dy=0 -> weight ly; dy=1 -> 1-ly
        if ((unsigned)y0 > 30u) continue;
        #pragma unroll
        for (int dx = 0; dx < 2; ++dx) {
            const int x0 = x - 1 + dx;
            if ((unsigned)x0 > 30u) continue;
            const int bin = (g * NBX + x0) * NBY + y0;
            int r = base[bin];
            const int e = r + cnt[bin];
            for (; r < e; ++r) {
                const float4 ra = binned[r];        // broadcast within group
                const unsigned ma = __float_as_uint(ra.x);
                const int n  = ma & 16383;
                const int z0 = (ma >> 14) & 31;
                const float wx = dx ? (1.f - ra.y) : ra.y;
                const float wy = dy ? (1.f - ra.z) : ra.z;
                const float lz = ra.w;
                const float v  = fmaf(vg[((size_t)n << 5) + f], scf, shf);
                const float vv = wx * wy * v;
                const int a0 = (z0 << 5) + (f ^ z0);
                const int a1 = ((z0 + 1) << 5) + (f ^ (z0 + 1));
                tg[a0] += (1.f - lz) * vv;          // group-serial: race-free
                tg[a1] += lz * vv;
            }
        }
    }
    __syncthreads();

    // write out[(g*F + i)*G3 + x*1024 + t], reading swizzled tile — conflict-free
    float* og = out + ((size_t)g << 20) + (x << 10);
    const int zz = t & 31;
    const int taddr = ((t >> 5) << 10) + (zz << 5);
    #pragma unroll
    for (int i = 0; i < 32; ++i) {
        og[((size_t)i << 15) + t] = tile[taddr + (i ^ zz)];
    }
}

// ---------------- Fallback: direct-layout global-atomic scatter ----------------
__global__ __launch_bounds__(256) void scatter_kernel(
    const float* __restrict__ vals, const float* __restrict__ keys,
    const float* __restrict__ orig, const float* __restrict__ Rm,
    const float* __restrict__ tv, const float* __restrict__ scale,
    const float* __restrict__ shift, float* __restrict__ out)
{
    const int bid   = blockIdx.x;
    const int g     = bid >> 5;
    const int chunk = bid & 31;
    const int b     = g >> 2;
    const int h     = g & 3;

    __shared__ float sc[32], sh[32], sR[9], st3[3], ksc[3], ksh[3];
    const int t = threadIdx.x;
    if (t < 32)      { sc[t] = scale[12 + h * 32 + t]; sh[t] = shift[12 + h * 32 + t]; }
    else if (t < 41) { sR[t - 32]  = Rm[h * 9 + (t - 32)]; }
    else if (t < 44) { st3[t - 41] = tv[h * 3 + (t - 41)]; }
    else if (t < 47) { ksc[t - 44] = scale[h * 3 + (t - 44)];
                       ksh[t - 44] = shift[h * 3 + (t - 44)]; }
    __syncthreads();

    float* const og = out + ((size_t)g << 20);

    #pragma unroll
    for (int pp = 0; pp < 2; ++pp) {
        const int n = (chunk << 9) + (pp << 8) + t;

        const float k0 = fmaf(keys[(size_t)(g * 3 + 0) * Nn + n], ksc[0], ksh[0]);
        const float k1 = fmaf(keys[(size_t)(g * 3 + 1) * Nn + n], ksc[1], ksh[1]);
        const float k2 = fmaf(keys[(size_t)(g * 3 + 2) * Nn + n], ksc[2], ksh[2]);
        const float p0 = orig[(size_t)(b * 3 + 0) * Nn + n] + k0;
        const float p1 = orig[(size_t)(b * 3 + 1) * Nn + n] + k1;
        const float p2 = orig[(size_t)(b * 3 + 2) * Nn + n] + k2;

        int   idx[3];
        float loc[3];
        #pragma unroll
        for (int d = 0; d < 3; ++d) {
            const float tk = fmaf(sR[d*3+0], p0, fmaf(sR[d*3+1], p1, fmaf(sR[d*3+2], p2, st3[d])));
            const float la = tanhf(tk);
            const float po = (la + 1.f) * 15.5f;
            float fi = floorf(po);
            fi = fminf(fmaxf(fi, 0.f), 30.f);
            idx[d] = (int)fi;
            loc[d] = po - fi;
        }
        const int cell = (idx[0] * Gg + idx[1]) * Gg + idx[2];

        float v[32];
        const float4* vp = reinterpret_cast<const float4*>(vals + ((size_t)g * Nn + n) * Ff);
        #pragma unroll
        for (int q = 0; q < 8; ++q) {
            const float4 xq = vp[q];
            v[4*q+0] = fmaf(xq.x, sc[4*q+0], sh[4*q+0]);
            v[4*q+1] = fmaf(xq.y, sc[4*q+1], sh[4*q+1]);
            v[4*q+2] = fmaf(xq.z, sc[4*q+2], sh[4*q+2]);
            v[4*q+3] = fmaf(xq.w, sc[4*q+3], sh[4*q+3]);
        }

        const float wx1 = loc[0], wx0 = 1.f - loc[0];
        const float wy1 = loc[1], wy0 = 1.f - loc[1];
        const float wz1 = loc[2], wz0 = 1.f - loc[2];
        const float cw[8] = { wx0*wy0*wz0, wx0*wy0*wz1, wx0*wy1*wz0, wx0*wy1*wz1,
                              wx1*wy0*wz0, wx1*wy0*wz1, wx1*wy1*wz0, wx1*wy1*wz1 };
        const int  co[8] = { 0, 1, 32, 33, 1024, 1025, 1056, 1057 };

        #pragma unroll
        for (int ff = 0; ff < 32; ++ff) {
            float* const pf = og + (size_t)ff * G3v + cell;
            const float vf = v[ff];
            #pragma unroll
            for (int c8 = 0; c8 < 8; ++c8) {
                atomicAdd(pf + co[c8], cw[c8] * vf);
            }
        }
    }
}

extern "C" void kernel_launch(void* const* d_in, const int* in_sizes, int n_in,
                              void* d_out, int out_size, void* d_ws, size_t ws_size,
                              hipStream_t stream)
{
    const float* X    = (const float*)d_in[0];
    const float* orig = (const float*)d_in[1];
    const float* W    = (const float*)d_in[2];
    const float* kg   = (const float*)d_in[3];
    const float* kb   = (const float*)d_in[4];
    const float* vg   = (const float*)d_in[5];
    const float* vb   = (const float*)d_in[6];
    const float* Rm   = (const float*)d_in[7];
    const float* tv   = (const float*)d_in[8];
    float* out = (float*)d_out;
    float* ws  = (float*)d_ws;

    // float-offset workspace layout
    float* vals  = ws;                          // 16,777,216
    float* keys  = ws + 16777216;               //  1,572,864
    float* gsum  = ws + 18350080;               // 140
    float* gsq   = gsum + 140;
    float* scale = gsum + 280;
    float* shift = scale + 140;
    int*   cnt    = (int*)(ws + 18350848);      // 30,752
    int*   basep  = (int*)(ws + 18381600);      // 30,752
    int*   cursor = (int*)(ws + 18412352);      // 30,752
    float4* rec    = (float4*)(ws + 18443104);  // 524,288 float4
    float4* binned = (float4*)(ws + 20540256);  // 524,288 float4
    const size_t need_bytes = (size_t)22637408 * sizeof(float);   // ~90.5 MiB

    hipMemsetAsync(gsum, 0, 280 * sizeof(float), stream);

    gemm_stats_kernel<<<1024, 256, 0, stream>>>(X, W, vals, keys, gsum, gsq);
    finalize_kernel<<<1, 256, 0, stream>>>(gsum, gsq, kg, kb, vg, vb, scale, shift);

    if (ws_size >= need_bytes) {
        hipMemsetAsync(cnt, 0, NBINS * sizeof(int), stream);
        points_kernel<<<2048, 256, 0, stream>>>(keys, orig, Rm, tv, scale, shift, rec, cnt);
        scan_kernel<<<1, 1024, 0, stream>>>(cnt, basep, cursor);
        fill_kernel<<<2048, 256, 0, stream>>>(rec, cursor, binned);
        gather_kernel<<<1024, 1024, 0, stream>>>(vals, binned, basep, cnt, scale, shift, out);
    } else {
        hipMemsetAsync(out, 0, (size_t)out_size * sizeof(float), stream);
        scatter_kernel<<<1024, 256, 0, stream>>>(vals, keys, orig, Rm, tv, scale, shift, out);
    }
}